// Round 5
// baseline (141.582 us; speedup 1.0000x reference)
//
#include <hip/hip_runtime.h>
#include <stdint.h>

typedef __bf16 bf16;
typedef bf16 bf16x2 __attribute__((ext_vector_type(2)));
typedef bf16 bf16x8 __attribute__((ext_vector_type(8)));
typedef float f32x4 __attribute__((ext_vector_type(4)));
typedef float f32x16 __attribute__((ext_vector_type(16)));
typedef uint32_t u32;
typedef uint16_t u16;
typedef u32 u32x4 __attribute__((ext_vector_type(4)));

#define BATCH 4
#define NSEQ  4096
#define DHEAD 128
#define GROUPS 4
#define KB    32
#define KVSPAN (NSEQ/GROUPS)      // 1024
#define NITER  (KVSPAN/KB)        // 32
#define LOG2E 1.44269504088896340736f
#define OROW  136                 // epilogue Obuf row stride (floats)

__device__ __forceinline__ u16 f2bf(float f) {
    u32 u = __builtin_bit_cast(u32, f);
    u += 0x7fff + ((u >> 16) & 1);   // RNE
    return (u16)(u >> 16);
}

// ---------------- prep: fp32 x -> bf16 Xb (row-major) + XbT (transposed) ----------------
__global__ __launch_bounds__(256) void prep_kernel(const float* __restrict__ x,
                                                   u16* __restrict__ Xb,
                                                   u16* __restrict__ XbT) {
    __shared__ u16 tile[64][65];
    int bid = blockIdx.x;
    int b  = bid >> 7;
    int nt = (bid >> 1) & 63;
    int dt = bid & 1;
    int n0 = nt * 64, d0 = dt * 64;
    int t = threadIdx.x;
    const float* xb = x + (size_t)b * NSEQ * DHEAD;
    u16* Xbb  = Xb  + (size_t)b * NSEQ * DHEAD;
    u16* XbTb = XbT + (size_t)b * DHEAD * NSEQ;
    #pragma unroll
    for (int i = 0; i < 16; i++) {
        int idx = t + i * 256;
        int r = idx >> 6, c = idx & 63;
        float f = xb[(size_t)(n0 + r) * DHEAD + d0 + c];
        u16 v = f2bf(f);
        Xbb[(size_t)(n0 + r) * DHEAD + d0 + c] = v;
        tile[r][c] = v;
    }
    __syncthreads();
    #pragma unroll
    for (int i = 0; i < 16; i++) {
        int idx = t + i * 256;
        int r = idx >> 6, c = idx & 63;
        XbTb[(size_t)(d0 + r) * NSEQ + n0 + c] = tile[c][r];
    }
}

// ---------------- flash attention: LDS-free main loop ----------------
// K fragments (QK^T A-op) and V^T fragments (PV A-op) are contiguous 16B/lane reads
// directly from L2-resident Xb/XbT. K is register-double-buffered; V is issue-early.
// P stays in-register via bf16 pack + permlane32_swap. No main-loop barriers.
__device__ __forceinline__ void load_k(bf16x8 (&k)[8], const u16* kp) {
    #pragma unroll
    for (int dc = 0; dc < 8; dc++)
        k[dc] = *(const bf16x8*)(const void*)(kp + dc * 16);
}

__device__ __forceinline__ void attn_tile(const bf16x8 (&kf)[8], const u16* vp,
                                          const bf16x8 (&qf)[8], f32x16 (&acc)[4],
                                          float& m, float& lsum) {
    f32x16 zz = {0.f,0.f,0.f,0.f,0.f,0.f,0.f,0.f,0.f,0.f,0.f,0.f,0.f,0.f,0.f,0.f};
    // issue V loads early; consumed after QK^T + softmax (~500 cyc of cover)
    bf16x8 vf[8];
    #pragma unroll
    for (int db = 0; db < 4; db++) {
        vf[2*db]   = *(const bf16x8*)(const void*)(vp + (size_t)db * 32 * NSEQ);
        vf[2*db+1] = *(const bf16x8*)(const void*)(vp + (size_t)db * 32 * NSEQ + 16);
    }

    // QK^T: S^T[kv][q], 8 d-chunks, 2 accumulator chains
    f32x16 sa = zz, sb = zz;
    #pragma unroll
    for (int dc = 0; dc < 8; dc += 2) {
        sa = __builtin_amdgcn_mfma_f32_32x32x16_bf16(kf[dc],     qf[dc],     sa, 0, 0, 0);
        sb = __builtin_amdgcn_mfma_f32_32x32x16_bf16(kf[dc + 1], qf[dc + 1], sb, 0, 0, 0);
    }
    f32x16 s = sa + sb;

    // online softmax (tree reductions); lane holds 16 kv rows for q = lane&31
    float red[8];
    #pragma unroll
    for (int i = 0; i < 8; i++) red[i] = fmaxf(s[i], s[i + 8]);
    #pragma unroll
    for (int i = 0; i < 4; i++) red[i] = fmaxf(red[i], red[i + 4]);
    float tmax = fmaxf(fmaxf(red[0], red[1]), fmaxf(red[2], red[3]));
    tmax = fmaxf(tmax, __shfl_xor(tmax, 32));   // lanes l <-> l+32 hold same q
    if (!__all(tmax <= m)) {      // exact defer-max: skip rescale when no new max
        float mnew = fmaxf(m, tmax);
        float sc = __builtin_amdgcn_exp2f((m - mnew) * LOG2E);
        lsum *= sc;
        #pragma unroll
        for (int db = 0; db < 4; db++) acc[db] *= sc;
        m = mnew;
    }
    float mL = m * LOG2E;
    float p[16];
    #pragma unroll
    for (int i = 0; i < 16; i++)
        p[i] = __builtin_amdgcn_exp2f(s[i] * LOG2E - mL);
    float ss[8];
    #pragma unroll
    for (int i = 0; i < 8; i++) ss[i] = p[i] + p[i + 8];
    #pragma unroll
    for (int i = 0; i < 4; i++) ss[i] += ss[i + 4];
    lsum += (ss[0] + ss[1]) + (ss[2] + ss[3]);

    // P -> bf16 pairs -> permlane32_swap -> PV B-fragments (no LDS)
    u32 c01   = __builtin_bit_cast(u32, (bf16x2){(bf16)p[0],  (bf16)p[1]});
    u32 c23   = __builtin_bit_cast(u32, (bf16x2){(bf16)p[2],  (bf16)p[3]});
    u32 c89   = __builtin_bit_cast(u32, (bf16x2){(bf16)p[4],  (bf16)p[5]});
    u32 c1011 = __builtin_bit_cast(u32, (bf16x2){(bf16)p[6],  (bf16)p[7]});
    u32 cA    = __builtin_bit_cast(u32, (bf16x2){(bf16)p[8],  (bf16)p[9]});
    u32 cB    = __builtin_bit_cast(u32, (bf16x2){(bf16)p[10], (bf16)p[11]});
    u32 cC    = __builtin_bit_cast(u32, (bf16x2){(bf16)p[12], (bf16)p[13]});
    u32 cD    = __builtin_bit_cast(u32, (bf16x2){(bf16)p[14], (bf16)p[15]});
    auto sA = __builtin_amdgcn_permlane32_swap(c01, c89,   false, false);
    auto sB = __builtin_amdgcn_permlane32_swap(c23, c1011, false, false);
    auto sC = __builtin_amdgcn_permlane32_swap(cA, cC,     false, false);
    auto sD = __builtin_amdgcn_permlane32_swap(cB, cD,     false, false);
    bf16x8 pb0 = __builtin_bit_cast(bf16x8, (u32x4){sA[0], sB[0], sA[1], sB[1]});
    bf16x8 pb1 = __builtin_bit_cast(bf16x8, (u32x4){sC[0], sD[0], sC[1], sD[1]});

    // PV: out^T += V^T . P^T, 4 d-blocks x 2 k-steps
    #pragma unroll
    for (int db = 0; db < 4; db++) {
        acc[db] = __builtin_amdgcn_mfma_f32_32x32x16_bf16(vf[2*db],     pb0, acc[db], 0, 0, 0);
        acc[db] = __builtin_amdgcn_mfma_f32_32x32x16_bf16(vf[2*db + 1], pb1, acc[db], 0, 0, 0);
    }
}

__global__ __launch_bounds__(512, 2) void attn_kernel(const u16* __restrict__ Xb,
                                                      const u16* __restrict__ XbT,
                                                      float* __restrict__ out) {
    __shared__ float Obuf[64 * OROW];          // 34.8 KB epilogue combine buffer
    __shared__ float Mx[GROUPS][64];
    __shared__ float Lx[GROUPS][64];

    int bid = blockIdx.x;            // 256 blocks, 1/CU
    int xcd = bid & 7, pos = bid >> 3;
    int b    = xcd >> 1;             // 2 XCDs per batch -> batch L2-resident
    int qblk = pos + ((xcd & 1) << 5);

    int t = threadIdx.x;
    int w = t >> 6, l = t & 63;
    int grp = w >> 1, wq = w & 1;
    int r  = l & 31;                 // lane row (m/n index)
    int hh = l >> 5;                 // k-half
    int qn = wq * 32 + r;            // q row within block (0..63)
    int q0 = qblk * 64 + qn;

    const u16* Xbb  = Xb  + (size_t)b * NSEQ * DHEAD;
    const u16* XbTb = XbT + (size_t)b * DHEAD * NSEQ;

    // Q B-fragments: col=q=r, k(d) = dc*16 + hh*8 + i
    bf16x8 qf[8];
    const u16* qrow = Xbb + (size_t)q0 * DHEAD;
    #pragma unroll
    for (int dc = 0; dc < 8; dc++)
        qf[dc] = *(const bf16x8*)(const void*)(qrow + dc * 16 + hh * 8);

    f32x16 zz = {0.f,0.f,0.f,0.f,0.f,0.f,0.f,0.f,0.f,0.f,0.f,0.f,0.f,0.f,0.f,0.f};
    f32x16 acc[4];                   // out^T d-blocks: d = db*32 + (reg&3)+8*(reg>>2)+4*hh, q=r
    acc[0] = zz; acc[1] = zz; acc[2] = zz; acc[3] = zz;
    float m = -1e30f, lsum = 0.f;

    int kvbase = grp * KVSPAN;
    // per-lane fragment base pointers (contiguous 16B per lane, MFMA A-layout)
    const u16* kp = Xbb  + (size_t)r * DHEAD + hh * 8;   // + kv*DHEAD + dc*16
    const u16* vp = XbTb + (size_t)r * NSEQ  + hh * 8;   // + kv + db*32*NSEQ (+16)

    bf16x8 kA[8], kB[8];
    load_k(kA, kp + (size_t)kvbase * DHEAD);
    for (int it = 0; it < NITER; it += 2) {
        int kv0 = kvbase + it * KB;
        load_k(kB, kp + (size_t)(kv0 + KB) * DHEAD);           // prefetch tile it+1
        attn_tile(kA, vp + kv0, qf, acc, m, lsum);
        if (it + 2 < NITER)
            load_k(kA, kp + (size_t)(kv0 + 2 * KB) * DHEAD);   // prefetch tile it+2
        attn_tile(kB, vp + kv0 + KB, qf, acc, m, lsum);
    }

    // ---- combine 4 kv-groups ----
    lsum += __shfl_xor(lsum, 32);    // cross-half total
    if (l < 32) { Mx[grp][qn] = m; Lx[grp][qn] = lsum; }
    __syncthreads();

    float mtot = fmaxf(fmaxf(Mx[0][qn], Mx[1][qn]), fmaxf(Mx[2][qn], Mx[3][qn]));
    float coef = __builtin_amdgcn_exp2f((m - mtot) * LOG2E);

    #pragma unroll
    for (int j = 0; j < GROUPS; j++) {
        if (grp == j) {
            #pragma unroll
            for (int db = 0; db < 4; db++) {
                #pragma unroll
                for (int rq = 0; rq < 4; rq++) {
                    int d0 = db * 32 + rq * 8 + hh * 4;
                    float* dst = Obuf + qn * OROW + d0;
                    f32x4 v = { acc[db][rq*4+0], acc[db][rq*4+1], acc[db][rq*4+2], acc[db][rq*4+3] };
                    v *= coef;
                    if (j > 0) v += *(const f32x4*)(const void*)dst;
                    *(f32x4*)(void*)dst = v;
                }
            }
        }
        __syncthreads();
    }

    // coalesced final store: thread t -> row q2 = t>>3, 16 floats at (t&7)*16
    int q2 = t >> 3;
    float mt = fmaxf(fmaxf(Mx[0][q2], Mx[1][q2]), fmaxf(Mx[2][q2], Mx[3][q2]));
    float lt = 0.f;
    #pragma unroll
    for (int j = 0; j < GROUPS; j++)
        lt += Lx[j][q2] * __builtin_amdgcn_exp2f((Mx[j][q2] - mt) * LOG2E);
    float inv = 1.0f / lt;
    const float* srow = Obuf + q2 * OROW + (t & 7) * 16;
    float* orow = out + ((size_t)b * NSEQ + qblk * 64 + q2) * DHEAD + (t & 7) * 16;
    #pragma unroll
    for (int k = 0; k < 4; k++) {
        f32x4 v = *(const f32x4*)(const void*)(srow + k * 4);
        v *= inv;
        *(f32x4*)(void*)(orow + k * 4) = v;
    }
}

extern "C" void kernel_launch(void* const* d_in, const int* in_sizes, int n_in,
                              void* d_out, int out_size, void* d_ws, size_t ws_size,
                              hipStream_t stream) {
    (void)in_sizes; (void)n_in; (void)out_size; (void)ws_size;
    const float* x = (const float*)d_in[0];
    float* out = (float*)d_out;
    u16* Xb  = (u16*)d_ws;
    u16* XbT = Xb + (size_t)BATCH * NSEQ * DHEAD;
    prep_kernel<<<512, 256, 0, stream>>>(x, Xb, XbT);
    attn_kernel<<<BATCH * (NSEQ / 64), 512, 0, stream>>>(Xb, XbT, out);
}

// Round 6
// 58.403 us; speedup vs baseline: 2.4242x; 2.4242x over previous
//
#include <hip/hip_runtime.h>
#include <stdint.h>

typedef __bf16 bf16;
typedef bf16 bf16x2 __attribute__((ext_vector_type(2)));
typedef bf16 bf16x8 __attribute__((ext_vector_type(8)));
typedef float f32x4 __attribute__((ext_vector_type(4)));
typedef float f32x16 __attribute__((ext_vector_type(16)));
typedef uint32_t u32;
typedef uint16_t u16;
typedef u32 u32x4 __attribute__((ext_vector_type(4)));

#define BATCH 4
#define NSEQ  4096
#define DHEAD 128
#define GROUPS 4
#define KB    32
#define KVSPAN (NSEQ/GROUPS)      // 1024
#define NITER  (KVSPAN/KB)        // 32
#define NKT    (NSEQ/KB)          // 128 packed tiles per batch
#define TILE_B 8192               // bytes per packed tile (Kp and Vp alike)
#define LOG2E 1.44269504088896340736f
#define OROW  136                 // epilogue Obuf row stride (floats)

__device__ __forceinline__ u16 f2bf(float f) {
    u32 u = __builtin_bit_cast(u32, f);
    u += 0x7fff + ((u >> 16) & 1);   // RNE
    return (u16)(u >> 16);
}

// ---------------- prep: fp32 x -> MFMA-fragment-packed bf16 Kp / Vp ----------------
// Kp[kt][dc][hh][r][i] = x[kt*32+r][dc*16+hh*8+i]          (K/Q fragment order)
// Vp[kt][s][db][hh][r][i] = x[kt*32+s*16+hh*8+i][db*32+r]  (V^T fragment order)
// A wave's fragment load is then lane*16B contiguous (1024B dense per instruction).
__global__ __launch_bounds__(256) void prep_kernel(const float* __restrict__ x,
                                                   char* __restrict__ Kp,
                                                   char* __restrict__ Vp) {
    __shared__ u16 lds[32][136];
    int bid = blockIdx.x;            // 512 blocks = b(4) x kt(128)
    int b = bid >> 7, kt = bid & 127;
    int t = threadIdx.x;
    const float* xt = x + ((size_t)b * NSEQ + kt * 32) * DHEAD;
    #pragma unroll
    for (int j = 0; j < 16; j++) {
        int idx = t + j * 256;
        int r = idx >> 7, c = idx & 127;
        lds[r][c] = f2bf(xt[r * DHEAD + c]);
    }
    __syncthreads();
    char* kout = Kp + (size_t)(b * NKT + kt) * TILE_B;
    char* vout = Vp + (size_t)(b * NKT + kt) * TILE_B;
    #pragma unroll
    for (int j = 0; j < 2; j++) {
        int slot = t + j * 256;      // 512 slots x 16B = 8KB each for K and V
        {   // K slot
            int dc = slot >> 6, hh = (slot >> 5) & 1, r = slot & 31;
            bf16x8 v = *(const bf16x8*)(const void*)(&lds[r][dc * 16 + hh * 8]);
            *(bf16x8*)(void*)(kout + slot * 16) = v;
        }
        {   // V slot (transpose gather from LDS)
            int s = slot >> 8, db = (slot >> 6) & 3, hh = (slot >> 5) & 1, r = slot & 31;
            u16 tmp[8];
            #pragma unroll
            for (int i = 0; i < 8; i++) tmp[i] = lds[s * 16 + hh * 8 + i][db * 32 + r];
            *(bf16x8*)(void*)(vout + slot * 16) = *(const bf16x8*)(const void*)tmp;
        }
    }
}

// ---------------- flash attention: LDS-free, barrier-free main loop ----------------
// All K/Q/V fragments are dense 16B/lane loads from the packed L2-resident buffers.
// K register-double-buffered; V issue-early inside the tile; P in-register via
// bf16 pack + permlane32_swap. Waves fully independent until the epilogue.
__device__ __forceinline__ void load_k(bf16x8 (&k)[8], const char* p) {
    #pragma unroll
    for (int dc = 0; dc < 8; dc++)
        k[dc] = *(const bf16x8*)(const void*)(p + dc * 1024);
}

__device__ __forceinline__ void attn_tile(const bf16x8 (&kf)[8], const char* vp,
                                          const bf16x8 (&qf)[8], f32x16 (&acc)[4],
                                          float& m, float& lsum) {
    f32x16 zz = {0.f,0.f,0.f,0.f,0.f,0.f,0.f,0.f,0.f,0.f,0.f,0.f,0.f,0.f,0.f,0.f};
    // issue V loads early; consumed after QK^T + softmax (~300+ cyc of cover)
    bf16x8 vf[8];
    #pragma unroll
    for (int db = 0; db < 4; db++) {
        vf[2*db]   = *(const bf16x8*)(const void*)(vp + db * 1024);          // s=0
        vf[2*db+1] = *(const bf16x8*)(const void*)(vp + 4096 + db * 1024);   // s=1
    }

    // QK^T: S^T[kv][q], 8 d-chunks, 2 accumulator chains
    f32x16 sa = zz, sb = zz;
    #pragma unroll
    for (int dc = 0; dc < 8; dc += 2) {
        sa = __builtin_amdgcn_mfma_f32_32x32x16_bf16(kf[dc],     qf[dc],     sa, 0, 0, 0);
        sb = __builtin_amdgcn_mfma_f32_32x32x16_bf16(kf[dc + 1], qf[dc + 1], sb, 0, 0, 0);
    }
    f32x16 s = sa + sb;

    // online softmax (tree reductions); lane holds 16 kv rows for q = lane&31
    float red[8];
    #pragma unroll
    for (int i = 0; i < 8; i++) red[i] = fmaxf(s[i], s[i + 8]);
    #pragma unroll
    for (int i = 0; i < 4; i++) red[i] = fmaxf(red[i], red[i + 4]);
    float tmax = fmaxf(fmaxf(red[0], red[1]), fmaxf(red[2], red[3]));
    tmax = fmaxf(tmax, __shfl_xor(tmax, 32));   // lanes l <-> l+32 hold same q
    if (!__all(tmax <= m)) {      // exact defer-max: skip rescale when no new max
        float mnew = fmaxf(m, tmax);
        float sc = __builtin_amdgcn_exp2f((m - mnew) * LOG2E);
        lsum *= sc;
        #pragma unroll
        for (int db = 0; db < 4; db++) acc[db] *= sc;
        m = mnew;
    }
    float mL = m * LOG2E;
    float p[16];
    #pragma unroll
    for (int i = 0; i < 16; i++)
        p[i] = __builtin_amdgcn_exp2f(s[i] * LOG2E - mL);
    float ss[8];
    #pragma unroll
    for (int i = 0; i < 8; i++) ss[i] = p[i] + p[i + 8];
    #pragma unroll
    for (int i = 0; i < 4; i++) ss[i] += ss[i + 4];
    lsum += (ss[0] + ss[1]) + (ss[2] + ss[3]);

    // P -> bf16 pairs -> permlane32_swap -> PV B-fragments (no LDS)
    u32 c01   = __builtin_bit_cast(u32, (bf16x2){(bf16)p[0],  (bf16)p[1]});
    u32 c23   = __builtin_bit_cast(u32, (bf16x2){(bf16)p[2],  (bf16)p[3]});
    u32 c89   = __builtin_bit_cast(u32, (bf16x2){(bf16)p[4],  (bf16)p[5]});
    u32 c1011 = __builtin_bit_cast(u32, (bf16x2){(bf16)p[6],  (bf16)p[7]});
    u32 cA    = __builtin_bit_cast(u32, (bf16x2){(bf16)p[8],  (bf16)p[9]});
    u32 cB    = __builtin_bit_cast(u32, (bf16x2){(bf16)p[10], (bf16)p[11]});
    u32 cC    = __builtin_bit_cast(u32, (bf16x2){(bf16)p[12], (bf16)p[13]});
    u32 cD    = __builtin_bit_cast(u32, (bf16x2){(bf16)p[14], (bf16)p[15]});
    auto sA = __builtin_amdgcn_permlane32_swap(c01, c89,   false, false);
    auto sB = __builtin_amdgcn_permlane32_swap(c23, c1011, false, false);
    auto sC = __builtin_amdgcn_permlane32_swap(cA, cC,     false, false);
    auto sD = __builtin_amdgcn_permlane32_swap(cB, cD,     false, false);
    bf16x8 pb0 = __builtin_bit_cast(bf16x8, (u32x4){sA[0], sB[0], sA[1], sB[1]});
    bf16x8 pb1 = __builtin_bit_cast(bf16x8, (u32x4){sC[0], sD[0], sC[1], sD[1]});

    // PV: out^T += V^T . P^T, 4 d-blocks x 2 k-steps
    #pragma unroll
    for (int db = 0; db < 4; db++) {
        acc[db] = __builtin_amdgcn_mfma_f32_32x32x16_bf16(vf[2*db],     pb0, acc[db], 0, 0, 0);
        acc[db] = __builtin_amdgcn_mfma_f32_32x32x16_bf16(vf[2*db + 1], pb1, acc[db], 0, 0, 0);
    }
}

__global__ __launch_bounds__(512, 2) void attn_kernel(const char* __restrict__ Kp,
                                                      const char* __restrict__ Vp,
                                                      float* __restrict__ out) {
    __shared__ float Obuf[64 * OROW];          // 34.8 KB epilogue combine buffer
    __shared__ float Mx[GROUPS][64];
    __shared__ float Lx[GROUPS][64];

    int bid = blockIdx.x;            // 256 blocks, 1/CU
    int xcd = bid & 7, pos = bid >> 3;
    int b    = xcd >> 1;             // 2 XCDs per batch -> batch (2MB packed) L2-resident
    int qblk = pos + ((xcd & 1) << 5);

    int t = threadIdx.x;
    int w = t >> 6, l = t & 63;
    int grp = w >> 1, wq = w & 1;
    int r  = l & 31;                 // lane row (m/n index)
    int hh = l >> 5;                 // k-half;  note hh*32 + r == l
    int qn = wq * 32 + r;            // q row within block (0..63)

    // per-lane packed bases: fragment load = base + kt*8192 + dc*1024 (+ s*4096)
    const char* Kpb = Kp + (size_t)b * NKT * TILE_B + (size_t)l * 16;
    const char* Vpb = Vp + (size_t)b * NKT * TILE_B + (size_t)l * 16;

    // Q B-fragments come from Kp (identical fragment layout), tile ktq
    int ktq = qblk * 2 + wq;
    bf16x8 qf[8];
    load_k(qf, Kpb + (size_t)ktq * TILE_B);

    f32x16 zz = {0.f,0.f,0.f,0.f,0.f,0.f,0.f,0.f,0.f,0.f,0.f,0.f,0.f,0.f,0.f,0.f};
    f32x16 acc[4];                   // out^T d-blocks: d = db*32 + (reg&3)+8*(reg>>2)+4*hh, q=r
    acc[0] = zz; acc[1] = zz; acc[2] = zz; acc[3] = zz;
    float m = -1e30f, lsum = 0.f;

    int kt0 = grp * NITER;           // this group's 32 packed tiles
    bf16x8 kA[8], kB[8];
    load_k(kA, Kpb + (size_t)kt0 * TILE_B);
    for (int it = 0; it < NITER; it += 2) {
        size_t ktb = (size_t)(kt0 + it) * TILE_B;
        load_k(kB, Kpb + ktb + TILE_B);                       // prefetch tile it+1
        attn_tile(kA, Vpb + ktb, qf, acc, m, lsum);
        if (it + 2 < NITER)
            load_k(kA, Kpb + ktb + 2 * TILE_B);               // prefetch tile it+2
        attn_tile(kB, Vpb + ktb + TILE_B, qf, acc, m, lsum);
    }

    // ---- combine 4 kv-groups ----
    lsum += __shfl_xor(lsum, 32);    // cross-half total
    if (l < 32) { Mx[grp][qn] = m; Lx[grp][qn] = lsum; }
    __syncthreads();

    float mtot = fmaxf(fmaxf(Mx[0][qn], Mx[1][qn]), fmaxf(Mx[2][qn], Mx[3][qn]));
    float coef = __builtin_amdgcn_exp2f((m - mtot) * LOG2E);

    #pragma unroll
    for (int j = 0; j < GROUPS; j++) {
        if (grp == j) {
            #pragma unroll
            for (int db = 0; db < 4; db++) {
                #pragma unroll
                for (int rq = 0; rq < 4; rq++) {
                    int d0 = db * 32 + rq * 8 + hh * 4;
                    float* dst = Obuf + qn * OROW + d0;
                    f32x4 v = { acc[db][rq*4+0], acc[db][rq*4+1], acc[db][rq*4+2], acc[db][rq*4+3] };
                    v *= coef;
                    if (j > 0) v += *(const f32x4*)(const void*)dst;
                    *(f32x4*)(void*)dst = v;
                }
            }
        }
        __syncthreads();
    }

    // coalesced final store: thread t -> row q2 = t>>3, 16 floats at (t&7)*16
    int q2 = t >> 3;
    float mt = fmaxf(fmaxf(Mx[0][q2], Mx[1][q2]), fmaxf(Mx[2][q2], Mx[3][q2]));
    float lt = 0.f;
    #pragma unroll
    for (int j = 0; j < GROUPS; j++)
        lt += Lx[j][q2] * __builtin_amdgcn_exp2f((Mx[j][q2] - mt) * LOG2E);
    float inv = 1.0f / lt;
    const float* srow = Obuf + q2 * OROW + (t & 7) * 16;
    float* orow = out + ((size_t)b * NSEQ + qblk * 64 + q2) * DHEAD + (t & 7) * 16;
    #pragma unroll
    for (int k = 0; k < 4; k++) {
        f32x4 v = *(const f32x4*)(const void*)(srow + k * 4);
        v *= inv;
        *(f32x4*)(void*)(orow + k * 4) = v;
    }
}

extern "C" void kernel_launch(void* const* d_in, const int* in_sizes, int n_in,
                              void* d_out, int out_size, void* d_ws, size_t ws_size,
                              hipStream_t stream) {
    (void)in_sizes; (void)n_in; (void)out_size; (void)ws_size;
    const float* x = (const float*)d_in[0];
    float* out = (float*)d_out;
    char* Kp = (char*)d_ws;                                    // 4 MB packed K/Q fragments
    char* Vp = Kp + (size_t)BATCH * NKT * TILE_B;              // 4 MB packed V^T fragments
    prep_kernel<<<BATCH * NKT, 256, 0, stream>>>(x, Kp, Vp);
    attn_kernel<<<BATCH * (NSEQ / 64), 512, 0, stream>>>(Kp, Vp, out);
}